// Round 2
// baseline (75.170 us; speedup 1.0000x reference)
//
#include <hip/hip_runtime.h>

// GaussianAnsatzNN: out[k,d] = sum_m theta[m] * N * exp(-0.5*||x_k - mu_m||^2) * (mu_{m,d} - x_{k,d})
// Means form a separable 20^3 grid. Factored form, R2 restructure:
//
//  - ONE block owns 64 k's completely: 8 waves, wave g handles 50 of the 400
//    flattened (i,j) pairs; partials reduced via 6KB LDS; out written once
//    with plain stores. -> ZERO atomics, ZERO memset, no theta LDS staging.
//  - theta row address is wave-uniform (g via readfirstlane) -> scalar s_load
//    from L2-hot theta feeding fmaf(sgpr, vgpr, vgpr).
//  - Ex_i*Ey_j fused into one exp per pair: exp(-0.5*(dx^2+dy^2)).
//  - Grid 256 blocks x 8 waves = 2 waves/SIMD, ~70 VGPR.

#define NG  20
#define KPB 512   // 8 waves; wave g handles ij in [g*50, g*50+50)
#define KB  64    // k's per block
#define NW  8     // waves per block

__global__ __launch_bounds__(KPB, 2) void gauss_factored_kernel(
    const float* __restrict__ x, const float* __restrict__ means,
    const float* __restrict__ theta, float* __restrict__ out) {
  __shared__ float sred[NW * KB * 3];   // per-wave partials, 6144 B

  const int tid = threadIdx.x;
  const int lane = tid & 63;
  const int g = __builtin_amdgcn_readfirstlane(tid >> 6);  // wave id, uniform

  const int k = blockIdx.x * KB + lane;   // K = 16384 = 256*64, exact
  const float x0 = x[k * 3 + 0];
  const float x1 = x[k * 3 + 1];
  const float x2 = x[k * 3 + 2];

  // Per-thread z-axis factors (registers; l is always a compile-time index).
  float Ez[NG], Ezp[NG];
#pragma unroll
  for (int l = 0; l < NG; ++l) {
    const float dz = x2 - means[l * 3 + 2];     // uniform -> scalar load
    const float e = __expf(-0.5f * dz * dz);
    Ez[l] = e;
    Ezp[l] = -dz * e;                           // Ez_l * (g_l - x2)
  }

  float o0 = 0.f, o1 = 0.f, o2 = 0.f;
  const int ij0 = g * 50;

#pragma unroll 10
  for (int p = 0; p < 50; ++p) {
    const int ij = ij0 + p;                     // scalar
    const int i = ij / NG, j = ij % NG;         // scalar magic-div
    const float gi = means[i * 1200];           // g_i = means[(i*400)*3 + 0]
    const float gj = means[j * 60 + 1];         // g_j = means[(j*20)*3 + 1]
    const float dx = x0 - gi;
    const float dy = x1 - gj;
    const float exy = __expf(-0.5f * fmaf(dx, dx, dy * dy));  // Ex_i*Ey_j, one exp

    const float* __restrict__ th = theta + ij * NG;  // wave-uniform -> s_load
    float aZ0 = 0.f, aZ1 = 0.f, aZp0 = 0.f, aZp1 = 0.f;
#pragma unroll
    for (int l = 0; l < NG; l += 2) {
      const float t0 = th[l], t1 = th[l + 1];
      aZ0  = fmaf(t0, Ez [l],     aZ0);
      aZp0 = fmaf(t0, Ezp[l],     aZp0);
      aZ1  = fmaf(t1, Ez [l + 1], aZ1);
      aZp1 = fmaf(t1, Ezp[l + 1], aZp1);
    }
    const float aZ = aZ0 + aZ1;
    const float aZp = aZp0 + aZp1;
    o0 = fmaf(-dx * exy, aZ,  o0);   // (g_i - x0) * Ex*Ey * sum_l th*Ez
    o1 = fmaf(-dy * exy, aZ,  o1);   // (g_j - x1) * Ex*Ey * sum_l th*Ez
    o2 = fmaf(      exy, aZp, o2);   // Ex*Ey * sum_l th*Ezp
  }

  // Per-wave partials -> LDS. Write stride 12B: 3L mod 32 distinct over 32
  // lanes, 2-way aliasing across half-waves (free).
  float* sr = &sred[(g * KB + lane) * 3];
  sr[0] = o0; sr[1] = o1; sr[2] = o2;
  __syncthreads();

  // Reduce 8 partials per output scalar; threads 0..191 own out[blk*192 + t].
  if (tid < KB * 3) {
    float s = 0.f;
#pragma unroll
    for (int g2 = 0; g2 < NW; ++g2) s += sred[g2 * (KB * 3) + tid];
    const float Nc = 0.06349363593424097f;  // (2*pi)^{-3/2}
    out[blockIdx.x * (KB * 3) + tid] = s * Nc;
  }
}

extern "C" void kernel_launch(void* const* d_in, const int* in_sizes, int n_in,
                              void* d_out, int out_size, void* d_ws, size_t ws_size,
                              hipStream_t stream) {
  const float* x = (const float*)d_in[0];      // (K, 3)
  const float* means = (const float*)d_in[1];  // (8000, 3)
  const float* theta = (const float*)d_in[2];  // (8000,)
  float* out = (float*)d_out;                  // (K, 3)

  const int K = in_sizes[0] / 3;

  // out is written exactly once by plain stores -> no memset, no atomics.
  dim3 grid(K / KB);
  gauss_factored_kernel<<<grid, KPB, 0, stream>>>(x, means, theta, out);
}

// Round 3
// 66.881 us; speedup vs baseline: 1.1239x; 1.1239x over previous
//
#include <hip/hip_runtime.h>

// GaussianAnsatzNN: out[k,d] = sum_m theta[m] * N * exp(-0.5*||x_k - mu_m||^2) * (mu_{m,d} - x_{k,d})
// Means form a separable 20^3 grid. Factored form, R3:
//
//  - ONE 1024-thread block (16 waves) owns 64 k's (k = lane). Wave g handles
//    25 of the 400 flattened (i,j) pairs -> 4096 waves = 4 waves/SIMD
//    (2x R2's TLP, to hide dependency + LDS latency).
//  - theta staged once to LDS (32 KB, L2-hot source); per-pair rows read as
//    wave-uniform ds_read_b128 broadcasts (~60cyc, conflict-free) instead of
//    R2's exposed ~300cyc s_loads (k$ thrashes at 8 waves x 4KB slices).
//  - Ex_i*Ey_j fused into one exp per pair. Zero atomics, zero memset,
//    single dispatch; 12 KB LDS tree reduction; ~70 VGPR.

#define NG    20
#define NPAIR (NG * NG)     // 400
#define KPB   1024          // 16 waves
#define KB    64            // k's per block (one per lane)
#define NW    16            // waves per block
#define PPW   (NPAIR / NW)  // 25 pairs per wave

__global__ __launch_bounds__(KPB, 1) void gauss_factored_kernel(
    const float* __restrict__ x, const float* __restrict__ means,
    const float* __restrict__ theta, float* __restrict__ out) {
  __shared__ float sth[NPAIR * NG];    // 32000 B: theta[ij*20 + l]
  __shared__ float sg[3 * NG];         // grid axis values
  __shared__ float sred[NW * KB * 3];  // 12288 B: per-wave partials

  const int tid = threadIdx.x;
  const int lane = tid & 63;
  const int g = __builtin_amdgcn_readfirstlane(tid >> 6);  // wave id, uniform

  // Stage theta (8000 floats = 2000 float4; 2 per thread).
  {
    const float4* th4 = (const float4*)theta;
    float4* s4 = (float4*)sth;
    for (int idx = tid; idx < NPAIR * NG / 4; idx += KPB) s4[idx] = th4[idx];
  }
  // Stage grid axis values: g_i = means[(i*400)*3+0], g_j = means[(j*20)*3+1], g_l = means[l*3+2]
  if (tid < 3 * NG) {
    const int axis = tid / NG, p = tid % NG;
    const int m = (axis == 0) ? p * 400 : (axis == 1) ? p * 20 : p;
    sg[tid] = means[m * 3 + axis];
  }
  __syncthreads();

  const int k = blockIdx.x * KB + lane;  // K = 16384 = 256*64, exact
  const float x0 = x[k * 3 + 0];
  const float x1 = x[k * 3 + 1];
  const float x2 = x[k * 3 + 2];

  // Per-thread z-axis factors (registers; l always a compile-time index).
  float Ez[NG], Ezp[NG];
#pragma unroll
  for (int l = 0; l < NG; ++l) {
    const float dz = x2 - sg[2 * NG + l];
    const float e = __expf(-0.5f * dz * dz);
    Ez[l] = e;
    Ezp[l] = -dz * e;  // Ez_l * (g_l - x2)
  }

  float o0 = 0.f, o1 = 0.f, o2 = 0.f;
  const int p0 = g * PPW;

#pragma unroll
  for (int p = 0; p < PPW; ++p) {
    const int ij = p0 + p;               // wave-uniform
    const int i = ij / NG, j = ij % NG;  // scalar magic-div
    const float dx = x0 - sg[i];
    const float dy = x1 - sg[NG + j];
    const float exy = __expf(-0.5f * fmaf(dx, dx, dy * dy));  // Ex_i*Ey_j

    // theta row: wave-uniform LDS address -> broadcast ds_read_b128, no conflicts.
    const float4* trow = (const float4*)(sth + ij * NG);  // 80B stride, 16B aligned
    float aZ0 = 0.f, aZ1 = 0.f, aZp0 = 0.f, aZp1 = 0.f;
#pragma unroll
    for (int l4 = 0; l4 < 5; ++l4) {
      const float4 t = trow[l4];
      aZ0  = fmaf(t.x, Ez [4 * l4 + 0], aZ0);
      aZp0 = fmaf(t.x, Ezp[4 * l4 + 0], aZp0);
      aZ1  = fmaf(t.y, Ez [4 * l4 + 1], aZ1);
      aZp1 = fmaf(t.y, Ezp[4 * l4 + 1], aZp1);
      aZ0  = fmaf(t.z, Ez [4 * l4 + 2], aZ0);
      aZp0 = fmaf(t.z, Ezp[4 * l4 + 2], aZp0);
      aZ1  = fmaf(t.w, Ez [4 * l4 + 3], aZ1);
      aZp1 = fmaf(t.w, Ezp[4 * l4 + 3], aZp1);
    }
    const float aZ = aZ0 + aZ1;
    const float aZp = aZp0 + aZp1;
    o0 = fmaf(-dx * exy, aZ,  o0);   // (g_i - x0) * Ex*Ey * sum_l th*Ez
    o1 = fmaf(-dy * exy, aZ,  o1);   // (g_j - x1) * Ex*Ey * sum_l th*Ez
    o2 = fmaf(      exy, aZp, o2);   // Ex*Ey * sum_l th*Ezp
  }

  // Per-wave partials -> LDS. Stride 12B: 3L mod 32 distinct over 32 lanes,
  // 2-way aliasing across half-waves (free).
  float* sr = &sred[(g * KB + lane) * 3];
  sr[0] = o0; sr[1] = o1; sr[2] = o2;
  __syncthreads();

  // Reduce 16 partials per output scalar; threads 0..191 own out[blk*192 + t].
  if (tid < KB * 3) {
    float s = 0.f;
#pragma unroll
    for (int g2 = 0; g2 < NW; ++g2) s += sred[g2 * (KB * 3) + tid];
    const float Nc = 0.06349363593424097f;  // (2*pi)^{-3/2}
    out[blockIdx.x * (KB * 3) + tid] = s * Nc;
  }
}

extern "C" void kernel_launch(void* const* d_in, const int* in_sizes, int n_in,
                              void* d_out, int out_size, void* d_ws, size_t ws_size,
                              hipStream_t stream) {
  const float* x = (const float*)d_in[0];      // (K, 3)
  const float* means = (const float*)d_in[1];  // (8000, 3)
  const float* theta = (const float*)d_in[2];  // (8000,)
  float* out = (float*)d_out;                  // (K, 3)

  const int K = in_sizes[0] / 3;

  // out written exactly once by plain stores -> no memset, no atomics.
  dim3 grid(K / KB);
  gauss_factored_kernel<<<grid, KPB, 0, stream>>>(x, means, theta, out);
}